// Round 1
// baseline (1027.363 us; speedup 1.0000x reference)
//
#include <hip/hip_runtime.h>

#define N_NODES 100000
#define N_EDGES 1600000
#define IN_CH 128
#define HID 64
#define OUT_CH 16
#define N_GRAPHS 512
#define NEG_SLOPE 0.2f

#define SCAN_TILE 1024
#define SCAN_NBLK ((N_NODES + SCAN_TILE - 1) / SCAN_TILE)  // 98

__device__ __forceinline__ float wave_sum64(float v) {
  #pragma unroll
  for (int o = 32; o > 0; o >>= 1) v += __shfl_xor(v, o, 64);
  return v;
}

// ---------------- CSR build ----------------

__global__ void k_degree(const int* __restrict__ dst, int* __restrict__ deg) {
  int e = blockIdx.x * 256 + threadIdx.x;
  if (e < N_EDGES) atomicAdd(&deg[dst[e]], 1);
}

__global__ void k_scan1(const int* __restrict__ deg, int* __restrict__ excl,
                        int* __restrict__ part) {
  __shared__ int lds[256];
  int b = blockIdx.x, t = threadIdx.x;
  int base = b * SCAN_TILE + t * 4;
  int v0 = (base + 0 < N_NODES) ? deg[base + 0] : 0;
  int v1 = (base + 1 < N_NODES) ? deg[base + 1] : 0;
  int v2 = (base + 2 < N_NODES) ? deg[base + 2] : 0;
  int v3 = (base + 3 < N_NODES) ? deg[base + 3] : 0;
  int local = v0 + v1 + v2 + v3;
  lds[t] = local;
  __syncthreads();
  for (int off = 1; off < 256; off <<= 1) {
    int x = 0;
    if (t >= off) x = lds[t - off];
    __syncthreads();
    lds[t] += x;
    __syncthreads();
  }
  int incl = lds[t];
  int ex = incl - local;
  if (t == 255) part[b] = incl;
  if (base + 0 < N_NODES) excl[base + 0] = ex;  ex += v0;
  if (base + 1 < N_NODES) excl[base + 1] = ex;  ex += v1;
  if (base + 2 < N_NODES) excl[base + 2] = ex;  ex += v2;
  if (base + 3 < N_NODES) excl[base + 3] = ex;
}

__global__ void k_scan2(int* part) {
  if (threadIdx.x == 0) {
    int run = 0;
    for (int b = 0; b < SCAN_NBLK; b++) { int v = part[b]; part[b] = run; run += v; }
  }
}

__global__ void k_scan3(int* __restrict__ row_ptr, const int* __restrict__ part,
                        int* __restrict__ cursor) {
  int i = blockIdx.x * 256 + threadIdx.x;
  if (i < N_NODES) {
    int v = row_ptr[i] + part[i >> 10];
    row_ptr[i] = v;
    cursor[i] = v;
  }
  if (i == 0) row_ptr[N_NODES] = N_EDGES;
}

__global__ void k_fill(const int* __restrict__ src, const int* __restrict__ dst,
                       int* __restrict__ cursor, int* __restrict__ adj) {
  int e = blockIdx.x * 256 + threadIdx.x;
  if (e < N_EDGES) {
    int pos = atomicAdd(&cursor[dst[e]], 1);
    adj[pos] = src[e];
  }
}

// ---------------- dual GEMM: xl = x@Wl+bl, xr = x@Wr+br ----------------
// block = 256 threads = 4 nodes x 64 features; x rows staged in LDS.

template <int K>
__global__ void k_dual_gemm(const float* __restrict__ x,
                            const float* __restrict__ Wl, const float* __restrict__ bl,
                            const float* __restrict__ Wr, const float* __restrict__ br,
                            float* __restrict__ xl, float* __restrict__ xr) {
  __shared__ float xs[4 * K];
  int f = threadIdx.x & 63;
  int nl = threadIdx.x >> 6;
  int node0 = blockIdx.x * 4;
  for (int i = threadIdx.x; i < 4 * K; i += 256) {
    int nn = i / K, kk = i % K;
    int gn = node0 + nn;
    xs[i] = (gn < N_NODES) ? x[gn * K + kk] : 0.f;
  }
  __syncthreads();
  float al = bl[f], ar = br[f];
  const float* xrow = &xs[nl * K];
  #pragma unroll 8
  for (int k = 0; k < K; k++) {
    float xv = xrow[k];
    al = fmaf(xv, Wl[k * 64 + f], al);
    ar = fmaf(xv, Wr[k * 64 + f], ar);
  }
  int node = node0 + nl;
  if (node < N_NODES) {
    xl[node * 64 + f] = al;
    xr[node * 64 + f] = ar;
  }
}

// ---------------- GATv2 layer: one wave per destination node ----------------
// Online softmax over {self-loop} ∪ CSR incoming edges.

__global__ void k_gat(const float* __restrict__ xl, const float* __restrict__ xr,
                      const float* __restrict__ att, const float* __restrict__ bias,
                      const int* __restrict__ row_ptr, const int* __restrict__ adj,
                      float* __restrict__ out, int do_relu) {
  int wid = (blockIdx.x * 256 + threadIdx.x) >> 6;
  int lane = threadIdx.x & 63;
  if (wid >= N_NODES) return;
  float xr_l = xr[wid * 64 + lane];
  float att_l = att[lane];

  // self-loop (appended by reference's add_self_loops)
  float xl_self = xl[wid * 64 + lane];
  float h0 = xl_self + xr_l;
  h0 = (h0 >= 0.f) ? h0 : NEG_SLOPE * h0;
  float m = wave_sum64(h0 * att_l);
  float z = 1.f;          // exp(e_self - m) = 1
  float acc = xl_self;    // * 1

  int beg = row_ptr[wid], end = row_ptr[wid + 1];
  for (int p = beg; p < end; p++) {
    int j = adj[p];
    float xlj = xl[j * 64 + lane];
    float hh = xlj + xr_l;
    hh = (hh >= 0.f) ? hh : NEG_SLOPE * hh;
    float e = wave_sum64(hh * att_l);
    float nm = fmaxf(m, e);
    float sc = __expf(m - nm);
    float w = __expf(e - nm);
    z = fmaf(z, sc, w);
    acc = fmaf(acc, sc, w * xlj);
    m = nm;
  }
  float r = acc / z + bias[lane];
  if (do_relu) r = fmaxf(r, 0.f);
  out[wid * 64 + lane] = r;
}

// ---------------- global mean pool (batch is sorted) ----------------

__device__ __forceinline__ int lower_bound_batch(const int* __restrict__ b, int key) {
  int lo = 0, hi = N_NODES;
  while (lo < hi) {
    int mid = (lo + hi) >> 1;
    if (b[mid] < key) lo = mid + 1; else hi = mid;
  }
  return lo;
}

__global__ void k_pool(const float* __restrict__ h, const int* __restrict__ batch,
                       float* __restrict__ gmean) {
  __shared__ int s_range[2];
  __shared__ float red[256];
  int g = blockIdx.x, t = threadIdx.x;
  if (t == 0) s_range[0] = lower_bound_batch(batch, g);
  if (t == 1) s_range[1] = lower_bound_batch(batch, g + 1);
  __syncthreads();
  int lo = s_range[0], hi = s_range[1];
  int f = t & 63, sub = t >> 6;
  float acc = 0.f;
  for (int n = lo + sub; n < hi; n += 4) acc += h[n * 64 + f];
  red[t] = acc;
  __syncthreads();
  if (sub == 0) {
    float s = red[f] + red[64 + f] + red[128 + f] + red[192 + f];
    int cnt = hi - lo;
    if (cnt < 1) cnt = 1;
    gmean[g * 64 + f] = s / (float)cnt;
  }
}

// ---------------- MLP head ----------------

__global__ void k_head1(const float* __restrict__ gmean, const float* __restrict__ W,
                        const float* __restrict__ b, float* __restrict__ y) {
  int idx = blockIdx.x * 256 + threadIdx.x;
  if (idx >= N_GRAPHS * 64) return;
  int gi = idx >> 6, f = idx & 63;
  float acc = b[f];
  #pragma unroll 8
  for (int k = 0; k < 64; k++) acc = fmaf(gmean[gi * 64 + k], W[k * 64 + f], acc);
  y[idx] = acc;
}

__global__ void k_bnstats(const float* __restrict__ y, float* __restrict__ mu,
                          float* __restrict__ rstd) {
  int f = threadIdx.x;
  if (f >= 64) return;
  float s = 0.f, ss = 0.f;
  for (int g = 0; g < N_GRAPHS; g++) {
    float v = y[g * 64 + f];
    s += v;
    ss += v * v;
  }
  float m = s / (float)N_GRAPHS;
  float var = ss / (float)N_GRAPHS - m * m;
  mu[f] = m;
  rstd[f] = rsqrtf(var + 1e-5f);
}

__global__ void k_head2(const float* __restrict__ y, const float* __restrict__ gamma,
                        const float* __restrict__ beta, const float* __restrict__ mu,
                        const float* __restrict__ rstd, const float* __restrict__ W2,
                        const float* __restrict__ b2, float* __restrict__ out) {
  int idx = blockIdx.x * 256 + threadIdx.x;
  if (idx >= N_GRAPHS * OUT_CH) return;
  int gi = idx >> 4, o = idx & 15;
  float acc = b2[o];
  #pragma unroll
  for (int k = 0; k < 64; k++) {
    float v = y[gi * 64 + k];
    v = gamma[k] * (v - mu[k]) * rstd[k] + beta[k];
    v = fmaxf(v, 0.f);
    acc = fmaf(v, W2[k * OUT_CH + o], acc);
  }
  // log_softmax over the 16 lanes sharing this row
  float mx = acc;
  #pragma unroll
  for (int w = 8; w > 0; w >>= 1) mx = fmaxf(mx, __shfl_xor(mx, w, 16));
  float ex = __expf(acc - mx);
  float s = ex;
  #pragma unroll
  for (int w = 8; w > 0; w >>= 1) s += __shfl_xor(s, w, 16);
  out[idx] = acc - mx - __logf(s);
}

// ---------------- launcher ----------------

extern "C" void kernel_launch(void* const* d_in, const int* in_sizes, int n_in,
                              void* d_out, int out_size, void* d_ws, size_t ws_size,
                              hipStream_t stream) {
  const float* x      = (const float*)d_in[0];
  const int*   edge   = (const int*)d_in[1];
  const int*   batch  = (const int*)d_in[2];
  const float* W_l1   = (const float*)d_in[3];
  const float* b_l1   = (const float*)d_in[4];
  const float* W_r1   = (const float*)d_in[5];
  const float* b_r1   = (const float*)d_in[6];
  const float* att1   = (const float*)d_in[7];
  const float* bias1  = (const float*)d_in[8];
  const float* W_l2   = (const float*)d_in[9];
  const float* b_l2   = (const float*)d_in[10];
  const float* W_r2   = (const float*)d_in[11];
  const float* b_r2   = (const float*)d_in[12];
  const float* att2   = (const float*)d_in[13];
  const float* bias2  = (const float*)d_in[14];
  const float* W_fc1  = (const float*)d_in[15];
  const float* b_fc1  = (const float*)d_in[16];
  const float* gamma  = (const float*)d_in[17];
  const float* beta   = (const float*)d_in[18];
  const float* W_fc2  = (const float*)d_in[19];
  const float* b_fc2  = (const float*)d_in[20];

  const int* src = edge;
  const int* dst = edge + N_EDGES;

  char* ws = (char*)d_ws;
  size_t off = 0;
  auto alloc = [&](size_t bytes) -> void* {
    off = (off + 255) & ~(size_t)255;
    void* p = ws + off;
    off += bytes;
    return p;
  };
  int* deg      = (int*)alloc((size_t)N_NODES * 4);
  int* row_ptr  = (int*)alloc((size_t)(N_NODES + 1) * 4);
  int* cursor   = (int*)alloc((size_t)N_NODES * 4);
  int* adj      = (int*)alloc((size_t)N_EDGES * 4);
  int* part     = (int*)alloc((size_t)SCAN_NBLK * 4);
  float* xl     = (float*)alloc((size_t)N_NODES * HID * 4);
  float* xr     = (float*)alloc((size_t)N_NODES * HID * 4);
  float* h      = (float*)alloc((size_t)N_NODES * HID * 4);
  float* gmean  = (float*)alloc((size_t)N_GRAPHS * HID * 4);
  float* y      = (float*)alloc((size_t)N_GRAPHS * HID * 4);
  float* mu     = (float*)alloc(64 * 4);
  float* rstd   = (float*)alloc(64 * 4);

  hipMemsetAsync(deg, 0, (size_t)N_NODES * 4, stream);

  k_degree<<<(N_EDGES + 255) / 256, 256, 0, stream>>>(dst, deg);
  k_scan1<<<SCAN_NBLK, 256, 0, stream>>>(deg, row_ptr, part);
  k_scan2<<<1, 64, 0, stream>>>(part);
  k_scan3<<<(N_NODES + 255) / 256, 256, 0, stream>>>(row_ptr, part, cursor);
  k_fill<<<(N_EDGES + 255) / 256, 256, 0, stream>>>(src, dst, cursor, adj);

  // layer 1
  k_dual_gemm<IN_CH><<<(N_NODES + 3) / 4, 256, 0, stream>>>(x, W_l1, b_l1, W_r1, b_r1, xl, xr);
  k_gat<<<(N_NODES + 3) / 4, 256, 0, stream>>>(xl, xr, att1, bias1, row_ptr, adj, h, 1);
  // layer 2
  k_dual_gemm<HID><<<(N_NODES + 3) / 4, 256, 0, stream>>>(h, W_l2, b_l2, W_r2, b_r2, xl, xr);
  k_gat<<<(N_NODES + 3) / 4, 256, 0, stream>>>(xl, xr, att2, bias2, row_ptr, adj, h, 0);

  // pool + head
  k_pool<<<N_GRAPHS, 256, 0, stream>>>(h, batch, gmean);
  k_head1<<<(N_GRAPHS * 64 + 255) / 256, 256, 0, stream>>>(gmean, W_fc1, b_fc1, y);
  k_bnstats<<<1, 64, 0, stream>>>(y, mu, rstd);
  k_head2<<<(N_GRAPHS * OUT_CH + 255) / 256, 256, 0, stream>>>(y, gamma, beta, mu, rstd,
                                                               W_fc2, b_fc2, (float*)d_out);
}

// Round 2
// 701.298 us; speedup vs baseline: 1.4649x; 1.4649x over previous
//
#include <hip/hip_runtime.h>

#define N_NODES 100000
#define N_EDGES 1600000
#define IN_CH 128
#define HID 64
#define OUT_CH 16
#define N_GRAPHS 512
#define NEG_SLOPE 0.2f

#define SCAN_TILE 1024
#define SCAN_NBLK ((N_NODES + SCAN_TILE - 1) / SCAN_TILE)  // 98

__device__ __forceinline__ float wave_sum64(float v) {
  #pragma unroll
  for (int o = 32; o > 0; o >>= 1) v += __shfl_xor(v, o, 64);
  return v;
}

__device__ __forceinline__ void wave_sum64_2(float& a, float& b) {
  #pragma unroll
  for (int o = 32; o > 0; o >>= 1) {
    a += __shfl_xor(a, o, 64);
    b += __shfl_xor(b, o, 64);
  }
}

// ---------------- CSR build ----------------

__global__ void k_degree(const int* __restrict__ dst, int* __restrict__ deg) {
  int e = blockIdx.x * 256 + threadIdx.x;
  if (e < N_EDGES) atomicAdd(&deg[dst[e]], 1);
}

__global__ void k_scan1(const int* __restrict__ deg, int* __restrict__ excl,
                        int* __restrict__ part) {
  __shared__ int lds[256];
  int b = blockIdx.x, t = threadIdx.x;
  int base = b * SCAN_TILE + t * 4;
  int v0 = (base + 0 < N_NODES) ? deg[base + 0] : 0;
  int v1 = (base + 1 < N_NODES) ? deg[base + 1] : 0;
  int v2 = (base + 2 < N_NODES) ? deg[base + 2] : 0;
  int v3 = (base + 3 < N_NODES) ? deg[base + 3] : 0;
  int local = v0 + v1 + v2 + v3;
  lds[t] = local;
  __syncthreads();
  for (int off = 1; off < 256; off <<= 1) {
    int x = 0;
    if (t >= off) x = lds[t - off];
    __syncthreads();
    lds[t] += x;
    __syncthreads();
  }
  int incl = lds[t];
  int ex = incl - local;
  if (t == 255) part[b] = incl;
  if (base + 0 < N_NODES) excl[base + 0] = ex;  ex += v0;
  if (base + 1 < N_NODES) excl[base + 1] = ex;  ex += v1;
  if (base + 2 < N_NODES) excl[base + 2] = ex;  ex += v2;
  if (base + 3 < N_NODES) excl[base + 3] = ex;
}

__global__ void k_scan2(int* part) {
  __shared__ int lds[128];
  int t = threadIdx.x;
  int v = (t < SCAN_NBLK) ? part[t] : 0;
  lds[t] = v;
  __syncthreads();
  for (int off = 1; off < 128; off <<= 1) {
    int x = 0;
    if (t >= off) x = lds[t - off];
    __syncthreads();
    lds[t] += x;
    __syncthreads();
  }
  if (t < SCAN_NBLK) part[t] = lds[t] - v;  // exclusive
}

__global__ void k_scan3(int* __restrict__ row_ptr, const int* __restrict__ part,
                        int* __restrict__ cursor) {
  int i = blockIdx.x * 256 + threadIdx.x;
  if (i < N_NODES) {
    int v = row_ptr[i] + part[i >> 10];
    row_ptr[i] = v;
    cursor[i] = v;
  }
  if (i == 0) row_ptr[N_NODES] = N_EDGES;
}

__global__ void k_fill(const int* __restrict__ src, const int* __restrict__ dst,
                       int* __restrict__ cursor, int* __restrict__ adj) {
  int e = blockIdx.x * 256 + threadIdx.x;
  if (e < N_EDGES) {
    int pos = atomicAdd(&cursor[dst[e]], 1);
    adj[pos] = src[e];
  }
}

// ---------------- dual GEMM: xl = x@Wl+bl, xr = x@Wr+br ----------------
// Register-blocked tile: 128 nodes x 128 feats (Wl||Wr), 256 threads,
// 8x8 micro-tile per thread, K chunked by 32 in LDS.

template <int K>
__global__ __launch_bounds__(256) void k_dual_gemm(
    const float* __restrict__ x,
    const float* __restrict__ Wl, const float* __restrict__ bl,
    const float* __restrict__ Wr, const float* __restrict__ br,
    float* __restrict__ xl, float* __restrict__ xr) {
  constexpr int KC = 32;
  constexpr int NCH = K / KC;
  __shared__ float xs[KC][128];  // [k][node] transposed
  __shared__ float ws[KC][128];  // [k][feat] f<64: Wl, f>=64: Wr

  int tid = threadIdx.x;
  int tx = tid & 15;   // feature group: f0 = tx*8
  int ty = tid >> 4;   // node group:    n0 = ty*8
  int nb = blockIdx.x * 128;

  float acc[8][8];
  #pragma unroll
  for (int i = 0; i < 8; i++)
    #pragma unroll
    for (int j = 0; j < 8; j++) acc[i][j] = 0.f;

  for (int c = 0; c < NCH; c++) {
    int kc = c * KC;
    if (c) __syncthreads();
    // stage x (transposed): 128 nodes x 32 k = 1024 float4, 4 per thread
    #pragma unroll
    for (int j = 0; j < 4; j++) {
      int idx = tid + 256 * j;
      int node = idx >> 3, q = idx & 7;
      int gn = nb + node;
      float4 v = make_float4(0.f, 0.f, 0.f, 0.f);
      if (gn < N_NODES) v = *(const float4*)&x[(size_t)gn * K + kc + q * 4];
      xs[q * 4 + 0][node] = v.x;
      xs[q * 4 + 1][node] = v.y;
      xs[q * 4 + 2][node] = v.z;
      xs[q * 4 + 3][node] = v.w;
    }
    // stage W combined: 32 k-rows x 128 feats = 1024 float4, 4 per thread
    #pragma unroll
    for (int j = 0; j < 4; j++) {
      int idx = tid + 256 * j;
      int k = idx >> 5, cc = idx & 31;
      float4 v;
      if (cc < 16) v = *(const float4*)&Wl[(size_t)(kc + k) * 64 + cc * 4];
      else         v = *(const float4*)&Wr[(size_t)(kc + k) * 64 + (cc - 16) * 4];
      *(float4*)&ws[k][cc * 4] = v;
    }
    __syncthreads();

    #pragma unroll 4
    for (int k = 0; k < KC; k++) {
      float4 a0 = *(const float4*)&xs[k][ty * 8];
      float4 a1 = *(const float4*)&xs[k][ty * 8 + 4];
      float4 b0 = *(const float4*)&ws[k][tx * 8];
      float4 b1 = *(const float4*)&ws[k][tx * 8 + 4];
      float av[8] = {a0.x, a0.y, a0.z, a0.w, a1.x, a1.y, a1.z, a1.w};
      float bv[8] = {b0.x, b0.y, b0.z, b0.w, b1.x, b1.y, b1.z, b1.w};
      #pragma unroll
      for (int i = 0; i < 8; i++)
        #pragma unroll
        for (int j = 0; j < 8; j++)
          acc[i][j] = fmaf(av[i], bv[j], acc[i][j]);
    }
  }

  // epilogue
  int f0 = tx * 8;
  float bb[8];
  #pragma unroll
  for (int j = 0; j < 8; j++)
    bb[j] = (f0 < 64) ? bl[f0 + j] : br[f0 - 64 + j];
  float* outp = (f0 < 64) ? xl : xr;
  int fo = (f0 < 64) ? f0 : f0 - 64;
  #pragma unroll
  for (int i = 0; i < 8; i++) {
    int node = nb + ty * 8 + i;
    if (node < N_NODES) {
      float4 o0 = make_float4(acc[i][0] + bb[0], acc[i][1] + bb[1],
                              acc[i][2] + bb[2], acc[i][3] + bb[3]);
      float4 o1 = make_float4(acc[i][4] + bb[4], acc[i][5] + bb[5],
                              acc[i][6] + bb[6], acc[i][7] + bb[7]);
      *(float4*)&outp[(size_t)node * 64 + fo] = o0;
      *(float4*)&outp[(size_t)node * 64 + fo + 4] = o1;
    }
  }
}

// ---------------- GATv2 layer: one wave per destination node ----------------

__global__ void k_gat(const float* __restrict__ xl, const float* __restrict__ xr,
                      const float* __restrict__ att, const float* __restrict__ bias,
                      const int* __restrict__ row_ptr, const int* __restrict__ adj,
                      float* __restrict__ out, int do_relu) {
  int wid = (blockIdx.x * 256 + threadIdx.x) >> 6;
  int lane = threadIdx.x & 63;
  if (wid >= N_NODES) return;
  float xr_l = xr[wid * 64 + lane];
  float att_l = att[lane];

  // self-loop
  float xl_self = xl[wid * 64 + lane];
  float h0 = xl_self + xr_l;
  h0 = (h0 >= 0.f) ? h0 : NEG_SLOPE * h0;
  float m = wave_sum64(h0 * att_l);
  float z = 1.f;
  float acc = xl_self;

  int beg = row_ptr[wid], end = row_ptr[wid + 1];
  int p = beg;
  for (; p + 1 < end; p += 2) {
    int j0 = adj[p], j1 = adj[p + 1];
    float xlj0 = xl[j0 * 64 + lane];
    float xlj1 = xl[j1 * 64 + lane];
    float h0_ = xlj0 + xr_l;
    float h1_ = xlj1 + xr_l;
    h0_ = (h0_ >= 0.f) ? h0_ : NEG_SLOPE * h0_;
    h1_ = (h1_ >= 0.f) ? h1_ : NEG_SLOPE * h1_;
    float e0 = h0_ * att_l, e1 = h1_ * att_l;
    wave_sum64_2(e0, e1);
    float nm = fmaxf(m, fmaxf(e0, e1));
    float sc = __expf(m - nm);
    float w0 = __expf(e0 - nm);
    float w1 = __expf(e1 - nm);
    z = fmaf(z, sc, w0 + w1);
    acc = fmaf(acc, sc, fmaf(w0, xlj0, w1 * xlj1));
    m = nm;
  }
  if (p < end) {
    int j = adj[p];
    float xlj = xl[j * 64 + lane];
    float hh = xlj + xr_l;
    hh = (hh >= 0.f) ? hh : NEG_SLOPE * hh;
    float e = wave_sum64(hh * att_l);
    float nm = fmaxf(m, e);
    float sc = __expf(m - nm);
    float w = __expf(e - nm);
    z = fmaf(z, sc, w);
    acc = fmaf(acc, sc, w * xlj);
    m = nm;
  }
  float r = acc / z + bias[lane];
  if (do_relu) r = fmaxf(r, 0.f);
  out[wid * 64 + lane] = r;
}

// ---------------- global mean pool (batch is sorted) ----------------

__device__ __forceinline__ int lower_bound_batch(const int* __restrict__ b, int key) {
  int lo = 0, hi = N_NODES;
  while (lo < hi) {
    int mid = (lo + hi) >> 1;
    if (b[mid] < key) lo = mid + 1; else hi = mid;
  }
  return lo;
}

__global__ void k_pool(const float* __restrict__ h, const int* __restrict__ batch,
                       float* __restrict__ gmean) {
  __shared__ int s_range[2];
  __shared__ float red[256];
  int g = blockIdx.x, t = threadIdx.x;
  if (t == 0) s_range[0] = lower_bound_batch(batch, g);
  if (t == 1) s_range[1] = lower_bound_batch(batch, g + 1);
  __syncthreads();
  int lo = s_range[0], hi = s_range[1];
  int f = t & 63, sub = t >> 6;
  float acc = 0.f;
  for (int n = lo + sub; n < hi; n += 4) acc += h[n * 64 + f];
  red[t] = acc;
  __syncthreads();
  if (sub == 0) {
    float s = red[f] + red[64 + f] + red[128 + f] + red[192 + f];
    int cnt = hi - lo;
    if (cnt < 1) cnt = 1;
    gmean[g * 64 + f] = s / (float)cnt;
  }
}

// ---------------- MLP head ----------------

__global__ void k_head1(const float* __restrict__ gmean, const float* __restrict__ W,
                        const float* __restrict__ b, float* __restrict__ y) {
  int idx = blockIdx.x * 256 + threadIdx.x;
  if (idx >= N_GRAPHS * 64) return;
  int gi = idx >> 6, f = idx & 63;
  float acc = b[f];
  #pragma unroll 8
  for (int k = 0; k < 64; k++) acc = fmaf(gmean[gi * 64 + k], W[k * 64 + f], acc);
  y[idx] = acc;
}

__global__ void k_bnstats(const float* __restrict__ y, float* __restrict__ mu,
                          float* __restrict__ rstd) {
  int f = threadIdx.x;
  if (f >= 64) return;
  float s = 0.f, ss = 0.f;
  for (int g = 0; g < N_GRAPHS; g++) {
    float v = y[g * 64 + f];
    s += v;
    ss += v * v;
  }
  float m = s / (float)N_GRAPHS;
  float var = ss / (float)N_GRAPHS - m * m;
  mu[f] = m;
  rstd[f] = rsqrtf(var + 1e-5f);
}

__global__ void k_head2(const float* __restrict__ y, const float* __restrict__ gamma,
                        const float* __restrict__ beta, const float* __restrict__ mu,
                        const float* __restrict__ rstd, const float* __restrict__ W2,
                        const float* __restrict__ b2, float* __restrict__ out) {
  int idx = blockIdx.x * 256 + threadIdx.x;
  if (idx >= N_GRAPHS * OUT_CH) return;
  int gi = idx >> 4, o = idx & 15;
  float acc = b2[o];
  #pragma unroll
  for (int k = 0; k < 64; k++) {
    float v = y[gi * 64 + k];
    v = gamma[k] * (v - mu[k]) * rstd[k] + beta[k];
    v = fmaxf(v, 0.f);
    acc = fmaf(v, W2[k * OUT_CH + o], acc);
  }
  float mx = acc;
  #pragma unroll
  for (int w = 8; w > 0; w >>= 1) mx = fmaxf(mx, __shfl_xor(mx, w, 16));
  float ex = __expf(acc - mx);
  float s = ex;
  #pragma unroll
  for (int w = 8; w > 0; w >>= 1) s += __shfl_xor(s, w, 16);
  out[idx] = acc - mx - __logf(s);
}

// ---------------- launcher ----------------

extern "C" void kernel_launch(void* const* d_in, const int* in_sizes, int n_in,
                              void* d_out, int out_size, void* d_ws, size_t ws_size,
                              hipStream_t stream) {
  const float* x      = (const float*)d_in[0];
  const int*   edge   = (const int*)d_in[1];
  const int*   batch  = (const int*)d_in[2];
  const float* W_l1   = (const float*)d_in[3];
  const float* b_l1   = (const float*)d_in[4];
  const float* W_r1   = (const float*)d_in[5];
  const float* b_r1   = (const float*)d_in[6];
  const float* att1   = (const float*)d_in[7];
  const float* bias1  = (const float*)d_in[8];
  const float* W_l2   = (const float*)d_in[9];
  const float* b_l2   = (const float*)d_in[10];
  const float* W_r2   = (const float*)d_in[11];
  const float* b_r2   = (const float*)d_in[12];
  const float* att2   = (const float*)d_in[13];
  const float* bias2  = (const float*)d_in[14];
  const float* W_fc1  = (const float*)d_in[15];
  const float* b_fc1  = (const float*)d_in[16];
  const float* gamma  = (const float*)d_in[17];
  const float* beta   = (const float*)d_in[18];
  const float* W_fc2  = (const float*)d_in[19];
  const float* b_fc2  = (const float*)d_in[20];

  const int* src = edge;
  const int* dst = edge + N_EDGES;

  char* ws = (char*)d_ws;
  size_t off = 0;
  auto alloc = [&](size_t bytes) -> void* {
    off = (off + 255) & ~(size_t)255;
    void* p = ws + off;
    off += bytes;
    return p;
  };
  int* deg      = (int*)alloc((size_t)N_NODES * 4);
  int* row_ptr  = (int*)alloc((size_t)(N_NODES + 1) * 4);
  int* cursor   = (int*)alloc((size_t)N_NODES * 4);
  int* adj      = (int*)alloc((size_t)N_EDGES * 4);
  int* part     = (int*)alloc((size_t)SCAN_NBLK * 4);
  float* xl     = (float*)alloc((size_t)N_NODES * HID * 4);
  float* xr     = (float*)alloc((size_t)N_NODES * HID * 4);
  float* h      = (float*)alloc((size_t)N_NODES * HID * 4);
  float* gmean  = (float*)alloc((size_t)N_GRAPHS * HID * 4);
  float* y      = (float*)alloc((size_t)N_GRAPHS * HID * 4);
  float* mu     = (float*)alloc(64 * 4);
  float* rstd   = (float*)alloc(64 * 4);

  hipMemsetAsync(deg, 0, (size_t)N_NODES * 4, stream);

  k_degree<<<(N_EDGES + 255) / 256, 256, 0, stream>>>(dst, deg);
  k_scan1<<<SCAN_NBLK, 256, 0, stream>>>(deg, row_ptr, part);
  k_scan2<<<1, 128, 0, stream>>>(part);
  k_scan3<<<(N_NODES + 255) / 256, 256, 0, stream>>>(row_ptr, part, cursor);
  k_fill<<<(N_EDGES + 255) / 256, 256, 0, stream>>>(src, dst, cursor, adj);

  // layer 1
  k_dual_gemm<IN_CH><<<(N_NODES + 127) / 128, 256, 0, stream>>>(x, W_l1, b_l1, W_r1, b_r1, xl, xr);
  k_gat<<<(N_NODES + 3) / 4, 256, 0, stream>>>(xl, xr, att1, bias1, row_ptr, adj, h, 1);
  // layer 2
  k_dual_gemm<HID><<<(N_NODES + 127) / 128, 256, 0, stream>>>(h, W_l2, b_l2, W_r2, b_r2, xl, xr);
  k_gat<<<(N_NODES + 3) / 4, 256, 0, stream>>>(xl, xr, att2, bias2, row_ptr, adj, h, 0);

  // pool + head
  k_pool<<<N_GRAPHS, 256, 0, stream>>>(h, batch, gmean);
  k_head1<<<(N_GRAPHS * 64 + 255) / 256, 256, 0, stream>>>(gmean, W_fc1, b_fc1, y);
  k_bnstats<<<1, 64, 0, stream>>>(y, mu, rstd);
  k_head2<<<(N_GRAPHS * OUT_CH + 255) / 256, 256, 0, stream>>>(y, gamma, beta, mu, rstd,
                                                               W_fc2, b_fc2, (float*)d_out);
}

// Round 3
// 596.499 us; speedup vs baseline: 1.7223x; 1.1757x over previous
//
#include <hip/hip_runtime.h>

#define N_NODES 100000
#define N_EDGES 1600000
#define IN_CH 128
#define HID 64
#define OUT_CH 16
#define N_GRAPHS 512
#define NEG_SLOPE 0.2f

#define SCAN_TILE 1024
#define SCAN_NBLK ((N_NODES + SCAN_TILE - 1) / SCAN_TILE)  // 98

// ---------------- CSR build ----------------

__global__ void k_degree(const int* __restrict__ dst, int* __restrict__ deg) {
  int e = blockIdx.x * 256 + threadIdx.x;
  if (e < N_EDGES) atomicAdd(&deg[dst[e]], 1);
}

__global__ void k_scan1(const int* __restrict__ deg, int* __restrict__ excl,
                        int* __restrict__ part) {
  __shared__ int lds[256];
  int b = blockIdx.x, t = threadIdx.x;
  int base = b * SCAN_TILE + t * 4;
  int v0 = (base + 0 < N_NODES) ? deg[base + 0] : 0;
  int v1 = (base + 1 < N_NODES) ? deg[base + 1] : 0;
  int v2 = (base + 2 < N_NODES) ? deg[base + 2] : 0;
  int v3 = (base + 3 < N_NODES) ? deg[base + 3] : 0;
  int local = v0 + v1 + v2 + v3;
  lds[t] = local;
  __syncthreads();
  for (int off = 1; off < 256; off <<= 1) {
    int x = 0;
    if (t >= off) x = lds[t - off];
    __syncthreads();
    lds[t] += x;
    __syncthreads();
  }
  int incl = lds[t];
  int ex = incl - local;
  if (t == 255) part[b] = incl;
  if (base + 0 < N_NODES) excl[base + 0] = ex;  ex += v0;
  if (base + 1 < N_NODES) excl[base + 1] = ex;  ex += v1;
  if (base + 2 < N_NODES) excl[base + 2] = ex;  ex += v2;
  if (base + 3 < N_NODES) excl[base + 3] = ex;
}

__global__ void k_scan2(int* part) {
  __shared__ int lds[128];
  int t = threadIdx.x;
  int v = (t < SCAN_NBLK) ? part[t] : 0;
  lds[t] = v;
  __syncthreads();
  for (int off = 1; off < 128; off <<= 1) {
    int x = 0;
    if (t >= off) x = lds[t - off];
    __syncthreads();
    lds[t] += x;
    __syncthreads();
  }
  if (t < SCAN_NBLK) part[t] = lds[t] - v;  // exclusive
}

__global__ void k_scan3(int* __restrict__ row_ptr, const int* __restrict__ part,
                        int* __restrict__ cursor) {
  int i = blockIdx.x * 256 + threadIdx.x;
  if (i < N_NODES) {
    int v = row_ptr[i] + part[i >> 10];
    row_ptr[i] = v;
    cursor[i] = v;
  }
  if (i == 0) row_ptr[N_NODES] = N_EDGES;
}

__global__ void k_fill(const int* __restrict__ src, const int* __restrict__ dst,
                       int* __restrict__ cursor, int* __restrict__ adj) {
  int e = blockIdx.x * 256 + threadIdx.x;
  if (e < N_EDGES) {
    int pos = atomicAdd(&cursor[dst[e]], 1);
    adj[pos] = src[e];
  }
}

// ---------------- dual GEMM: xl = x@Wl+bl, xr = x@Wr+br ----------------

template <int K>
__global__ __launch_bounds__(256) void k_dual_gemm(
    const float* __restrict__ x,
    const float* __restrict__ Wl, const float* __restrict__ bl,
    const float* __restrict__ Wr, const float* __restrict__ br,
    float* __restrict__ xl, float* __restrict__ xr) {
  constexpr int KC = 32;
  constexpr int NCH = K / KC;
  __shared__ float xs[KC][128];  // [k][node] transposed
  __shared__ float ws[KC][128];  // [k][feat] f<64: Wl, f>=64: Wr

  int tid = threadIdx.x;
  int tx = tid & 15;   // feature group: f0 = tx*8
  int ty = tid >> 4;   // node group:    n0 = ty*8
  int nb = blockIdx.x * 128;

  float acc[8][8];
  #pragma unroll
  for (int i = 0; i < 8; i++)
    #pragma unroll
    for (int j = 0; j < 8; j++) acc[i][j] = 0.f;

  for (int c = 0; c < NCH; c++) {
    int kc = c * KC;
    if (c) __syncthreads();
    #pragma unroll
    for (int j = 0; j < 4; j++) {
      int idx = tid + 256 * j;
      int node = idx >> 3, q = idx & 7;
      int gn = nb + node;
      float4 v = make_float4(0.f, 0.f, 0.f, 0.f);
      if (gn < N_NODES) v = *(const float4*)&x[(size_t)gn * K + kc + q * 4];
      xs[q * 4 + 0][node] = v.x;
      xs[q * 4 + 1][node] = v.y;
      xs[q * 4 + 2][node] = v.z;
      xs[q * 4 + 3][node] = v.w;
    }
    #pragma unroll
    for (int j = 0; j < 4; j++) {
      int idx = tid + 256 * j;
      int k = idx >> 5, cc = idx & 31;
      float4 v;
      if (cc < 16) v = *(const float4*)&Wl[(size_t)(kc + k) * 64 + cc * 4];
      else         v = *(const float4*)&Wr[(size_t)(kc + k) * 64 + (cc - 16) * 4];
      *(float4*)&ws[k][cc * 4] = v;
    }
    __syncthreads();

    #pragma unroll 4
    for (int k = 0; k < KC; k++) {
      float4 a0 = *(const float4*)&xs[k][ty * 8];
      float4 a1 = *(const float4*)&xs[k][ty * 8 + 4];
      float4 b0 = *(const float4*)&ws[k][tx * 8];
      float4 b1 = *(const float4*)&ws[k][tx * 8 + 4];
      float av[8] = {a0.x, a0.y, a0.z, a0.w, a1.x, a1.y, a1.z, a1.w};
      float bv[8] = {b0.x, b0.y, b0.z, b0.w, b1.x, b1.y, b1.z, b1.w};
      #pragma unroll
      for (int i = 0; i < 8; i++)
        #pragma unroll
        for (int j = 0; j < 8; j++)
          acc[i][j] = fmaf(av[i], bv[j], acc[i][j]);
    }
  }

  int f0 = tx * 8;
  float bb[8];
  #pragma unroll
  for (int j = 0; j < 8; j++)
    bb[j] = (f0 < 64) ? bl[f0 + j] : br[f0 - 64 + j];
  float* outp = (f0 < 64) ? xl : xr;
  int fo = (f0 < 64) ? f0 : f0 - 64;
  #pragma unroll
  for (int i = 0; i < 8; i++) {
    int node = nb + ty * 8 + i;
    if (node < N_NODES) {
      float4 o0 = make_float4(acc[i][0] + bb[0], acc[i][1] + bb[1],
                              acc[i][2] + bb[2], acc[i][3] + bb[3]);
      float4 o1 = make_float4(acc[i][4] + bb[4], acc[i][5] + bb[5],
                              acc[i][6] + bb[6], acc[i][7] + bb[7]);
      *(float4*)&outp[(size_t)node * 64 + fo] = o0;
      *(float4*)&outp[(size_t)node * 64 + fo + 4] = o1;
    }
  }
}

// ---------------- GATv2 layer ----------------
// One wave per dst node. Lane = sub(2b)*16 + fg(4b): 4 edges in flight,
// 16 lanes x float4 features per edge. Per-subgroup online softmax
// partials (m, z, acc4) merged via xor-shuffle {16,32} at the end.
// Sentinel -1e30 (not -inf): exp underflows to 0, no NaN.

#define NEG_BIG (-1e30f)

__global__ __launch_bounds__(256) void k_gat(
    const float* __restrict__ xl, const float* __restrict__ xr,
    const float* __restrict__ att, const float* __restrict__ bias,
    const int* __restrict__ row_ptr, const int* __restrict__ adj,
    float* __restrict__ out, int do_relu) {
  int wid = (blockIdx.x * 256 + threadIdx.x) >> 6;
  int lane = threadIdx.x & 63;
  if (wid >= N_NODES) return;
  int fg = lane & 15;   // feature group: feats [fg*4, fg*4+4)
  int sub = lane >> 4;  // edge slot 0..3

  float4 xr4 = *(const float4*)&xr[(size_t)wid * 64 + fg * 4];
  float4 att4 = *(const float4*)&att[fg * 4];

  int beg = row_ptr[wid];
  int L = row_ptr[wid + 1] - beg + 1;  // virtual list: self-loop + CSR edges

  float m = NEG_BIG, z = 0.f;
  float4 acc = make_float4(0.f, 0.f, 0.f, 0.f);

  for (int p0 = 0; p0 < L; p0 += 4) {
    int q = p0 + sub;
    bool active = (q < L);
    int j = wid;
    if (active && q > 0) j = adj[beg + q - 1];
    float4 v = make_float4(0.f, 0.f, 0.f, 0.f);
    if (active) v = *(const float4*)&xl[(size_t)j * 64 + fg * 4];

    float hx = v.x + xr4.x; hx = (hx >= 0.f) ? hx : NEG_SLOPE * hx;
    float hy = v.y + xr4.y; hy = (hy >= 0.f) ? hy : NEG_SLOPE * hy;
    float hz = v.z + xr4.z; hz = (hz >= 0.f) ? hz : NEG_SLOPE * hz;
    float hw = v.w + xr4.w; hw = (hw >= 0.f) ? hw : NEG_SLOPE * hw;
    float s = fmaf(hx, att4.x, fmaf(hy, att4.y, fmaf(hz, att4.z, hw * att4.w)));
    #pragma unroll
    for (int o = 1; o <= 8; o <<= 1) s += __shfl_xor(s, o, 64);
    float e = active ? s : NEG_BIG;

    float nm = fmaxf(m, e);
    float sc = __expf(m - nm);
    float w = __expf(e - nm);
    z = fmaf(z, sc, w);
    acc.x = fmaf(acc.x, sc, w * v.x);
    acc.y = fmaf(acc.y, sc, w * v.y);
    acc.z = fmaf(acc.z, sc, w * v.z);
    acc.w = fmaf(acc.w, sc, w * v.w);
    m = nm;
  }

  // merge the 4 subgroup partials (same fg across subs = same features)
  #pragma unroll
  for (int o = 16; o <= 32; o <<= 1) {
    float m2 = __shfl_xor(m, o, 64);
    float z2 = __shfl_xor(z, o, 64);
    float a0 = __shfl_xor(acc.x, o, 64);
    float a1 = __shfl_xor(acc.y, o, 64);
    float a2 = __shfl_xor(acc.z, o, 64);
    float a3 = __shfl_xor(acc.w, o, 64);
    float nm = fmaxf(m, m2);
    float s1 = __expf(m - nm);
    float s2 = __expf(m2 - nm);
    z = z * s1 + z2 * s2;
    acc.x = acc.x * s1 + a0 * s2;
    acc.y = acc.y * s1 + a1 * s2;
    acc.z = acc.z * s1 + a2 * s2;
    acc.w = acc.w * s1 + a3 * s2;
    m = nm;
  }

  if (sub == 0) {
    float4 b4 = *(const float4*)&bias[fg * 4];
    float inv = 1.f / z;
    float4 r;
    r.x = acc.x * inv + b4.x;
    r.y = acc.y * inv + b4.y;
    r.z = acc.z * inv + b4.z;
    r.w = acc.w * inv + b4.w;
    if (do_relu) {
      r.x = fmaxf(r.x, 0.f); r.y = fmaxf(r.y, 0.f);
      r.z = fmaxf(r.z, 0.f); r.w = fmaxf(r.w, 0.f);
    }
    *(float4*)&out[(size_t)wid * 64 + fg * 4] = r;
  }
}

// ---------------- global mean pool (batch is sorted) ----------------

__device__ __forceinline__ int lower_bound_batch(const int* __restrict__ b, int key) {
  int lo = 0, hi = N_NODES;
  while (lo < hi) {
    int mid = (lo + hi) >> 1;
    if (b[mid] < key) lo = mid + 1; else hi = mid;
  }
  return lo;
}

__global__ void k_pool(const float* __restrict__ h, const int* __restrict__ batch,
                       float* __restrict__ gmean) {
  __shared__ int s_range[2];
  __shared__ float red[256];
  int g = blockIdx.x, t = threadIdx.x;
  if (t == 0) s_range[0] = lower_bound_batch(batch, g);
  if (t == 1) s_range[1] = lower_bound_batch(batch, g + 1);
  __syncthreads();
  int lo = s_range[0], hi = s_range[1];
  int f = t & 63, sub = t >> 6;
  float acc = 0.f;
  for (int n = lo + sub; n < hi; n += 4) acc += h[n * 64 + f];
  red[t] = acc;
  __syncthreads();
  if (sub == 0) {
    float s = red[f] + red[64 + f] + red[128 + f] + red[192 + f];
    int cnt = hi - lo;
    if (cnt < 1) cnt = 1;
    gmean[g * 64 + f] = s / (float)cnt;
  }
}

// ---------------- MLP head ----------------

__global__ void k_head1(const float* __restrict__ gmean, const float* __restrict__ W,
                        const float* __restrict__ b, float* __restrict__ y) {
  int idx = blockIdx.x * 256 + threadIdx.x;
  if (idx >= N_GRAPHS * 64) return;
  int gi = idx >> 6, f = idx & 63;
  float acc = b[f];
  #pragma unroll 8
  for (int k = 0; k < 64; k++) acc = fmaf(gmean[gi * 64 + k], W[k * 64 + f], acc);
  y[idx] = acc;
}

__global__ void k_bnstats(const float* __restrict__ y, float* __restrict__ mu,
                          float* __restrict__ rstd) {
  int f = threadIdx.x;
  if (f >= 64) return;
  float s = 0.f, ss = 0.f;
  for (int g = 0; g < N_GRAPHS; g++) {
    float v = y[g * 64 + f];
    s += v;
    ss += v * v;
  }
  float m = s / (float)N_GRAPHS;
  float var = ss / (float)N_GRAPHS - m * m;
  mu[f] = m;
  rstd[f] = rsqrtf(var + 1e-5f);
}

__global__ void k_head2(const float* __restrict__ y, const float* __restrict__ gamma,
                        const float* __restrict__ beta, const float* __restrict__ mu,
                        const float* __restrict__ rstd, const float* __restrict__ W2,
                        const float* __restrict__ b2, float* __restrict__ out) {
  int idx = blockIdx.x * 256 + threadIdx.x;
  if (idx >= N_GRAPHS * OUT_CH) return;
  int gi = idx >> 4, o = idx & 15;
  float acc = b2[o];
  #pragma unroll
  for (int k = 0; k < 64; k++) {
    float v = y[gi * 64 + k];
    v = gamma[k] * (v - mu[k]) * rstd[k] + beta[k];
    v = fmaxf(v, 0.f);
    acc = fmaf(v, W2[k * OUT_CH + o], acc);
  }
  float mx = acc;
  #pragma unroll
  for (int w = 8; w > 0; w >>= 1) mx = fmaxf(mx, __shfl_xor(mx, w, 16));
  float ex = __expf(acc - mx);
  float s = ex;
  #pragma unroll
  for (int w = 8; w > 0; w >>= 1) s += __shfl_xor(s, w, 16);
  out[idx] = acc - mx - __logf(s);
}

// ---------------- launcher ----------------

extern "C" void kernel_launch(void* const* d_in, const int* in_sizes, int n_in,
                              void* d_out, int out_size, void* d_ws, size_t ws_size,
                              hipStream_t stream) {
  const float* x      = (const float*)d_in[0];
  const int*   edge   = (const int*)d_in[1];
  const int*   batch  = (const int*)d_in[2];
  const float* W_l1   = (const float*)d_in[3];
  const float* b_l1   = (const float*)d_in[4];
  const float* W_r1   = (const float*)d_in[5];
  const float* b_r1   = (const float*)d_in[6];
  const float* att1   = (const float*)d_in[7];
  const float* bias1  = (const float*)d_in[8];
  const float* W_l2   = (const float*)d_in[9];
  const float* b_l2   = (const float*)d_in[10];
  const float* W_r2   = (const float*)d_in[11];
  const float* b_r2   = (const float*)d_in[12];
  const float* att2   = (const float*)d_in[13];
  const float* bias2  = (const float*)d_in[14];
  const float* W_fc1  = (const float*)d_in[15];
  const float* b_fc1  = (const float*)d_in[16];
  const float* gamma  = (const float*)d_in[17];
  const float* beta   = (const float*)d_in[18];
  const float* W_fc2  = (const float*)d_in[19];
  const float* b_fc2  = (const float*)d_in[20];

  const int* src = edge;
  const int* dst = edge + N_EDGES;

  char* ws = (char*)d_ws;
  size_t off = 0;
  auto alloc = [&](size_t bytes) -> void* {
    off = (off + 255) & ~(size_t)255;
    void* p = ws + off;
    off += bytes;
    return p;
  };
  int* deg      = (int*)alloc((size_t)N_NODES * 4);
  int* row_ptr  = (int*)alloc((size_t)(N_NODES + 1) * 4);
  int* cursor   = (int*)alloc((size_t)N_NODES * 4);
  int* adj      = (int*)alloc((size_t)N_EDGES * 4);
  int* part     = (int*)alloc((size_t)SCAN_NBLK * 4);
  float* xl     = (float*)alloc((size_t)N_NODES * HID * 4);
  float* xr     = (float*)alloc((size_t)N_NODES * HID * 4);
  float* h      = (float*)alloc((size_t)N_NODES * HID * 4);
  float* gmean  = (float*)alloc((size_t)N_GRAPHS * HID * 4);
  float* y      = (float*)alloc((size_t)N_GRAPHS * HID * 4);
  float* mu     = (float*)alloc(64 * 4);
  float* rstd   = (float*)alloc(64 * 4);

  hipMemsetAsync(deg, 0, (size_t)N_NODES * 4, stream);

  k_degree<<<(N_EDGES + 255) / 256, 256, 0, stream>>>(dst, deg);
  k_scan1<<<SCAN_NBLK, 256, 0, stream>>>(deg, row_ptr, part);
  k_scan2<<<1, 128, 0, stream>>>(part);
  k_scan3<<<(N_NODES + 255) / 256, 256, 0, stream>>>(row_ptr, part, cursor);
  k_fill<<<(N_EDGES + 255) / 256, 256, 0, stream>>>(src, dst, cursor, adj);

  // layer 1
  k_dual_gemm<IN_CH><<<(N_NODES + 127) / 128, 256, 0, stream>>>(x, W_l1, b_l1, W_r1, b_r1, xl, xr);
  k_gat<<<(N_NODES + 3) / 4, 256, 0, stream>>>(xl, xr, att1, bias1, row_ptr, adj, h, 1);
  // layer 2
  k_dual_gemm<HID><<<(N_NODES + 127) / 128, 256, 0, stream>>>(h, W_l2, b_l2, W_r2, b_r2, xl, xr);
  k_gat<<<(N_NODES + 3) / 4, 256, 0, stream>>>(xl, xr, att2, bias2, row_ptr, adj, h, 0);

  // pool + head
  k_pool<<<N_GRAPHS, 256, 0, stream>>>(h, batch, gmean);
  k_head1<<<(N_GRAPHS * 64 + 255) / 256, 256, 0, stream>>>(gmean, W_fc1, b_fc1, y);
  k_bnstats<<<1, 64, 0, stream>>>(y, mu, rstd);
  k_head2<<<(N_GRAPHS * OUT_CH + 255) / 256, 256, 0, stream>>>(y, gamma, beta, mu, rstd,
                                                               W_fc2, b_fc2, (float*)d_out);
}

// Round 4
// 497.883 us; speedup vs baseline: 2.0635x; 1.1981x over previous
//
#include <hip/hip_runtime.h>

#define N_NODES 100000
#define N_EDGES 1600000
#define IN_CH 128
#define HID 64
#define OUT_CH 16
#define N_GRAPHS 512
#define NEG_SLOPE 0.2f

#define SCAN_TILE 1024
#define SCAN_NBLK ((N_NODES + SCAN_TILE - 1) / SCAN_TILE)  // 98

#define GEMM1_BLOCKS ((N_NODES + 127) / 128)               // 782
#define DEG_EPT 4                                          // edges per thread
#define DEG_BLOCKS ((N_EDGES + 256 * DEG_EPT - 1) / (256 * DEG_EPT))  // 1563
#define FUSED_BLOCKS (GEMM1_BLOCKS + DEG_BLOCKS)           // 2345

// ---------------- fused: layer-1 dual GEMM  +  degree/rank pass ----------------
// blockIdx % 3 == 0 -> GEMM tile (782 blocks), else degree+rank (1563 blocks).
// Latency-bound atomic waves co-schedule with VALU-bound GEMM waves on the
// same CUs, hiding the atomic path under FMA issue.

__global__ __launch_bounds__(256) void k_fused_gemm1_degree(
    const float* __restrict__ x,
    const float* __restrict__ Wl, const float* __restrict__ bl,
    const float* __restrict__ Wr, const float* __restrict__ br,
    float* __restrict__ xl, float* __restrict__ xr,
    const int* __restrict__ dst, int* __restrict__ deg, int* __restrict__ rank) {
  constexpr int K = IN_CH;
  constexpr int KC = 32;
  constexpr int NCH = K / KC;
  __shared__ float xs[KC][128];
  __shared__ float ws[KC][128];

  int b = blockIdx.x;
  if (b % 3 != 0) {
    // ---- degree + rank: one atomic per edge, rank = old count ----
    int db = b - b / 3 - 1;  // 0..DEG_BLOCKS-1
    int base = (db * 256 + threadIdx.x) * DEG_EPT;
    if (base + DEG_EPT <= N_EDGES) {
      int4 d4 = *(const int4*)&dst[base];
      int4 r4;
      r4.x = atomicAdd(&deg[d4.x], 1);
      r4.y = atomicAdd(&deg[d4.y], 1);
      r4.z = atomicAdd(&deg[d4.z], 1);
      r4.w = atomicAdd(&deg[d4.w], 1);
      *(int4*)&rank[base] = r4;
    } else {
      for (int e = base; e < N_EDGES; e++)
        rank[e] = atomicAdd(&deg[dst[e]], 1);
    }
    return;
  }

  // ---- GEMM tile ----
  int tid = threadIdx.x;
  int tx = tid & 15;
  int ty = tid >> 4;
  int nb = (b / 3) * 128;

  float acc[8][8];
  #pragma unroll
  for (int i = 0; i < 8; i++)
    #pragma unroll
    for (int j = 0; j < 8; j++) acc[i][j] = 0.f;

  for (int c = 0; c < NCH; c++) {
    int kc = c * KC;
    if (c) __syncthreads();
    #pragma unroll
    for (int j = 0; j < 4; j++) {
      int idx = tid + 256 * j;
      int node = idx >> 3, q = idx & 7;
      int gn = nb + node;
      float4 v = make_float4(0.f, 0.f, 0.f, 0.f);
      if (gn < N_NODES) v = *(const float4*)&x[(size_t)gn * K + kc + q * 4];
      xs[q * 4 + 0][node] = v.x;
      xs[q * 4 + 1][node] = v.y;
      xs[q * 4 + 2][node] = v.z;
      xs[q * 4 + 3][node] = v.w;
    }
    #pragma unroll
    for (int j = 0; j < 4; j++) {
      int idx = tid + 256 * j;
      int k = idx >> 5, cc = idx & 31;
      float4 v;
      if (cc < 16) v = *(const float4*)&Wl[(size_t)(kc + k) * 64 + cc * 4];
      else         v = *(const float4*)&Wr[(size_t)(kc + k) * 64 + (cc - 16) * 4];
      *(float4*)&ws[k][cc * 4] = v;
    }
    __syncthreads();

    #pragma unroll 4
    for (int k = 0; k < KC; k++) {
      float4 a0 = *(const float4*)&xs[k][ty * 8];
      float4 a1 = *(const float4*)&xs[k][ty * 8 + 4];
      float4 b0 = *(const float4*)&ws[k][tx * 8];
      float4 b1 = *(const float4*)&ws[k][tx * 8 + 4];
      float av[8] = {a0.x, a0.y, a0.z, a0.w, a1.x, a1.y, a1.z, a1.w};
      float bv[8] = {b0.x, b0.y, b0.z, b0.w, b1.x, b1.y, b1.z, b1.w};
      #pragma unroll
      for (int i = 0; i < 8; i++)
        #pragma unroll
        for (int j = 0; j < 8; j++)
          acc[i][j] = fmaf(av[i], bv[j], acc[i][j]);
    }
  }

  int f0 = tx * 8;
  float bb[8];
  #pragma unroll
  for (int j = 0; j < 8; j++)
    bb[j] = (f0 < 64) ? bl[f0 + j] : br[f0 - 64 + j];
  float* outp = (f0 < 64) ? xl : xr;
  int fo = (f0 < 64) ? f0 : f0 - 64;
  #pragma unroll
  for (int i = 0; i < 8; i++) {
    int node = nb + ty * 8 + i;
    if (node < N_NODES) {
      float4 o0 = make_float4(acc[i][0] + bb[0], acc[i][1] + bb[1],
                              acc[i][2] + bb[2], acc[i][3] + bb[3]);
      float4 o1 = make_float4(acc[i][4] + bb[4], acc[i][5] + bb[5],
                              acc[i][6] + bb[6], acc[i][7] + bb[7]);
      *(float4*)&outp[(size_t)node * 64 + fo] = o0;
      *(float4*)&outp[(size_t)node * 64 + fo + 4] = o1;
    }
  }
}

// ---------------- CSR scan ----------------

__global__ void k_scan1(const int* __restrict__ deg, int* __restrict__ excl,
                        int* __restrict__ part) {
  __shared__ int lds[256];
  int b = blockIdx.x, t = threadIdx.x;
  int base = b * SCAN_TILE + t * 4;
  int v0 = (base + 0 < N_NODES) ? deg[base + 0] : 0;
  int v1 = (base + 1 < N_NODES) ? deg[base + 1] : 0;
  int v2 = (base + 2 < N_NODES) ? deg[base + 2] : 0;
  int v3 = (base + 3 < N_NODES) ? deg[base + 3] : 0;
  int local = v0 + v1 + v2 + v3;
  lds[t] = local;
  __syncthreads();
  for (int off = 1; off < 256; off <<= 1) {
    int x = 0;
    if (t >= off) x = lds[t - off];
    __syncthreads();
    lds[t] += x;
    __syncthreads();
  }
  int incl = lds[t];
  int ex = incl - local;
  if (t == 255) part[b] = incl;
  if (base + 0 < N_NODES) excl[base + 0] = ex;  ex += v0;
  if (base + 1 < N_NODES) excl[base + 1] = ex;  ex += v1;
  if (base + 2 < N_NODES) excl[base + 2] = ex;  ex += v2;
  if (base + 3 < N_NODES) excl[base + 3] = ex;
}

__global__ void k_scan2(int* part) {
  __shared__ int lds[128];
  int t = threadIdx.x;
  int v = (t < SCAN_NBLK) ? part[t] : 0;
  lds[t] = v;
  __syncthreads();
  for (int off = 1; off < 128; off <<= 1) {
    int x = 0;
    if (t >= off) x = lds[t - off];
    __syncthreads();
    lds[t] += x;
    __syncthreads();
  }
  if (t < SCAN_NBLK) part[t] = lds[t] - v;  // exclusive
}

__global__ void k_scan3(int* __restrict__ row_ptr, const int* __restrict__ part) {
  int i = blockIdx.x * 256 + threadIdx.x;
  if (i < N_NODES) row_ptr[i] += part[i >> 10];
  if (i == 0) row_ptr[N_NODES] = N_EDGES;
}

// ---------------- fill (atomic-free): adj[row_ptr[dst] + rank] = src ----------------

__global__ void k_fill2(const int* __restrict__ src, const int* __restrict__ dst,
                        const int* __restrict__ rank, const int* __restrict__ row_ptr,
                        int* __restrict__ adj) {
  int base = (blockIdx.x * 256 + threadIdx.x) * DEG_EPT;
  if (base + DEG_EPT <= N_EDGES) {
    int4 d4 = *(const int4*)&dst[base];
    int4 s4 = *(const int4*)&src[base];
    int4 r4 = *(const int4*)&rank[base];
    adj[row_ptr[d4.x] + r4.x] = s4.x;
    adj[row_ptr[d4.y] + r4.y] = s4.y;
    adj[row_ptr[d4.z] + r4.z] = s4.z;
    adj[row_ptr[d4.w] + r4.w] = s4.w;
  } else {
    for (int e = base; e < N_EDGES; e++)
      adj[row_ptr[dst[e]] + rank[e]] = src[e];
  }
}

// ---------------- layer-2 dual GEMM ----------------

template <int K>
__global__ __launch_bounds__(256) void k_dual_gemm(
    const float* __restrict__ x,
    const float* __restrict__ Wl, const float* __restrict__ bl,
    const float* __restrict__ Wr, const float* __restrict__ br,
    float* __restrict__ xl, float* __restrict__ xr) {
  constexpr int KC = 32;
  constexpr int NCH = K / KC;
  __shared__ float xs[KC][128];
  __shared__ float ws[KC][128];

  int tid = threadIdx.x;
  int tx = tid & 15;
  int ty = tid >> 4;
  int nb = blockIdx.x * 128;

  float acc[8][8];
  #pragma unroll
  for (int i = 0; i < 8; i++)
    #pragma unroll
    for (int j = 0; j < 8; j++) acc[i][j] = 0.f;

  for (int c = 0; c < NCH; c++) {
    int kc = c * KC;
    if (c) __syncthreads();
    #pragma unroll
    for (int j = 0; j < 4; j++) {
      int idx = tid + 256 * j;
      int node = idx >> 3, q = idx & 7;
      int gn = nb + node;
      float4 v = make_float4(0.f, 0.f, 0.f, 0.f);
      if (gn < N_NODES) v = *(const float4*)&x[(size_t)gn * K + kc + q * 4];
      xs[q * 4 + 0][node] = v.x;
      xs[q * 4 + 1][node] = v.y;
      xs[q * 4 + 2][node] = v.z;
      xs[q * 4 + 3][node] = v.w;
    }
    #pragma unroll
    for (int j = 0; j < 4; j++) {
      int idx = tid + 256 * j;
      int k = idx >> 5, cc = idx & 31;
      float4 v;
      if (cc < 16) v = *(const float4*)&Wl[(size_t)(kc + k) * 64 + cc * 4];
      else         v = *(const float4*)&Wr[(size_t)(kc + k) * 64 + (cc - 16) * 4];
      *(float4*)&ws[k][cc * 4] = v;
    }
    __syncthreads();

    #pragma unroll 4
    for (int k = 0; k < KC; k++) {
      float4 a0 = *(const float4*)&xs[k][ty * 8];
      float4 a1 = *(const float4*)&xs[k][ty * 8 + 4];
      float4 b0 = *(const float4*)&ws[k][tx * 8];
      float4 b1 = *(const float4*)&ws[k][tx * 8 + 4];
      float av[8] = {a0.x, a0.y, a0.z, a0.w, a1.x, a1.y, a1.z, a1.w};
      float bv[8] = {b0.x, b0.y, b0.z, b0.w, b1.x, b1.y, b1.z, b1.w};
      #pragma unroll
      for (int i = 0; i < 8; i++)
        #pragma unroll
        for (int j = 0; j < 8; j++)
          acc[i][j] = fmaf(av[i], bv[j], acc[i][j]);
    }
  }

  int f0 = tx * 8;
  float bb[8];
  #pragma unroll
  for (int j = 0; j < 8; j++)
    bb[j] = (f0 < 64) ? bl[f0 + j] : br[f0 - 64 + j];
  float* outp = (f0 < 64) ? xl : xr;
  int fo = (f0 < 64) ? f0 : f0 - 64;
  #pragma unroll
  for (int i = 0; i < 8; i++) {
    int node = nb + ty * 8 + i;
    if (node < N_NODES) {
      float4 o0 = make_float4(acc[i][0] + bb[0], acc[i][1] + bb[1],
                              acc[i][2] + bb[2], acc[i][3] + bb[3]);
      float4 o1 = make_float4(acc[i][4] + bb[4], acc[i][5] + bb[5],
                              acc[i][6] + bb[6], acc[i][7] + bb[7]);
      *(float4*)&outp[(size_t)node * 64 + fo] = o0;
      *(float4*)&outp[(size_t)node * 64 + fo + 4] = o1;
    }
  }
}

// ---------------- GATv2 layer ----------------
// One wave per dst node. Lane = sub(2b)*16 + fg(4b): 4 edges in flight,
// 16 lanes x float4 features per edge. Sentinel -1e30: no NaN.

#define NEG_BIG (-1e30f)

__global__ __launch_bounds__(256) void k_gat(
    const float* __restrict__ xl, const float* __restrict__ xr,
    const float* __restrict__ att, const float* __restrict__ bias,
    const int* __restrict__ row_ptr, const int* __restrict__ adj,
    float* __restrict__ out, int do_relu) {
  int wid = (blockIdx.x * 256 + threadIdx.x) >> 6;
  int lane = threadIdx.x & 63;
  if (wid >= N_NODES) return;
  int fg = lane & 15;
  int sub = lane >> 4;

  float4 xr4 = *(const float4*)&xr[(size_t)wid * 64 + fg * 4];
  float4 att4 = *(const float4*)&att[fg * 4];

  int beg = row_ptr[wid];
  int L = row_ptr[wid + 1] - beg + 1;  // self-loop + CSR edges

  float m = NEG_BIG, z = 0.f;
  float4 acc = make_float4(0.f, 0.f, 0.f, 0.f);

  for (int p0 = 0; p0 < L; p0 += 4) {
    int q = p0 + sub;
    bool active = (q < L);
    int j = wid;
    if (active && q > 0) j = adj[beg + q - 1];
    float4 v = make_float4(0.f, 0.f, 0.f, 0.f);
    if (active) v = *(const float4*)&xl[(size_t)j * 64 + fg * 4];

    float hx = v.x + xr4.x; hx = (hx >= 0.f) ? hx : NEG_SLOPE * hx;
    float hy = v.y + xr4.y; hy = (hy >= 0.f) ? hy : NEG_SLOPE * hy;
    float hz = v.z + xr4.z; hz = (hz >= 0.f) ? hz : NEG_SLOPE * hz;
    float hw = v.w + xr4.w; hw = (hw >= 0.f) ? hw : NEG_SLOPE * hw;
    float s = fmaf(hx, att4.x, fmaf(hy, att4.y, fmaf(hz, att4.z, hw * att4.w)));
    #pragma unroll
    for (int o = 1; o <= 8; o <<= 1) s += __shfl_xor(s, o, 64);
    float e = active ? s : NEG_BIG;

    float nm = fmaxf(m, e);
    float sc = __expf(m - nm);
    float w = __expf(e - nm);
    z = fmaf(z, sc, w);
    acc.x = fmaf(acc.x, sc, w * v.x);
    acc.y = fmaf(acc.y, sc, w * v.y);
    acc.z = fmaf(acc.z, sc, w * v.z);
    acc.w = fmaf(acc.w, sc, w * v.w);
    m = nm;
  }

  #pragma unroll
  for (int o = 16; o <= 32; o <<= 1) {
    float m2 = __shfl_xor(m, o, 64);
    float z2 = __shfl_xor(z, o, 64);
    float a0 = __shfl_xor(acc.x, o, 64);
    float a1 = __shfl_xor(acc.y, o, 64);
    float a2 = __shfl_xor(acc.z, o, 64);
    float a3 = __shfl_xor(acc.w, o, 64);
    float nm = fmaxf(m, m2);
    float s1 = __expf(m - nm);
    float s2 = __expf(m2 - nm);
    z = z * s1 + z2 * s2;
    acc.x = acc.x * s1 + a0 * s2;
    acc.y = acc.y * s1 + a1 * s2;
    acc.z = acc.z * s1 + a2 * s2;
    acc.w = acc.w * s1 + a3 * s2;
    m = nm;
  }

  if (sub == 0) {
    float4 b4 = *(const float4*)&bias[fg * 4];
    float inv = 1.f / z;
    float4 r;
    r.x = acc.x * inv + b4.x;
    r.y = acc.y * inv + b4.y;
    r.z = acc.z * inv + b4.z;
    r.w = acc.w * inv + b4.w;
    if (do_relu) {
      r.x = fmaxf(r.x, 0.f); r.y = fmaxf(r.y, 0.f);
      r.z = fmaxf(r.z, 0.f); r.w = fmaxf(r.w, 0.f);
    }
    *(float4*)&out[(size_t)wid * 64 + fg * 4] = r;
  }
}

// ---------------- global mean pool (batch is sorted) ----------------

__device__ __forceinline__ int lower_bound_batch(const int* __restrict__ b, int key) {
  int lo = 0, hi = N_NODES;
  while (lo < hi) {
    int mid = (lo + hi) >> 1;
    if (b[mid] < key) lo = mid + 1; else hi = mid;
  }
  return lo;
}

__global__ void k_pool(const float* __restrict__ h, const int* __restrict__ batch,
                       float* __restrict__ gmean) {
  __shared__ int s_range[2];
  __shared__ float red[256];
  int g = blockIdx.x, t = threadIdx.x;
  if (t == 0) s_range[0] = lower_bound_batch(batch, g);
  if (t == 1) s_range[1] = lower_bound_batch(batch, g + 1);
  __syncthreads();
  int lo = s_range[0], hi = s_range[1];
  int f = t & 63, sub = t >> 6;
  float acc = 0.f;
  for (int n = lo + sub; n < hi; n += 4) acc += h[n * 64 + f];
  red[t] = acc;
  __syncthreads();
  if (sub == 0) {
    float s = red[f] + red[64 + f] + red[128 + f] + red[192 + f];
    int cnt = hi - lo;
    if (cnt < 1) cnt = 1;
    gmean[g * 64 + f] = s / (float)cnt;
  }
}

// ---------------- MLP head ----------------

__global__ void k_head1(const float* __restrict__ gmean, const float* __restrict__ W,
                        const float* __restrict__ b, float* __restrict__ y) {
  int idx = blockIdx.x * 256 + threadIdx.x;
  if (idx >= N_GRAPHS * 64) return;
  int gi = idx >> 6, f = idx & 63;
  float acc = b[f];
  #pragma unroll 8
  for (int k = 0; k < 64; k++) acc = fmaf(gmean[gi * 64 + k], W[k * 64 + f], acc);
  y[idx] = acc;
}

__global__ void k_bnstats(const float* __restrict__ y, float* __restrict__ mu,
                          float* __restrict__ rstd) {
  int f = threadIdx.x;
  if (f >= 64) return;
  float s = 0.f, ss = 0.f;
  for (int g = 0; g < N_GRAPHS; g++) {
    float v = y[g * 64 + f];
    s += v;
    ss += v * v;
  }
  float m = s / (float)N_GRAPHS;
  float var = ss / (float)N_GRAPHS - m * m;
  mu[f] = m;
  rstd[f] = rsqrtf(var + 1e-5f);
}

__global__ void k_head2(const float* __restrict__ y, const float* __restrict__ gamma,
                        const float* __restrict__ beta, const float* __restrict__ mu,
                        const float* __restrict__ rstd, const float* __restrict__ W2,
                        const float* __restrict__ b2, float* __restrict__ out) {
  int idx = blockIdx.x * 256 + threadIdx.x;
  if (idx >= N_GRAPHS * OUT_CH) return;
  int gi = idx >> 4, o = idx & 15;
  float acc = b2[o];
  #pragma unroll
  for (int k = 0; k < 64; k++) {
    float v = y[gi * 64 + k];
    v = gamma[k] * (v - mu[k]) * rstd[k] + beta[k];
    v = fmaxf(v, 0.f);
    acc = fmaf(v, W2[k * OUT_CH + o], acc);
  }
  float mx = acc;
  #pragma unroll
  for (int w = 8; w > 0; w >>= 1) mx = fmaxf(mx, __shfl_xor(mx, w, 16));
  float ex = __expf(acc - mx);
  float s = ex;
  #pragma unroll
  for (int w = 8; w > 0; w >>= 1) s += __shfl_xor(s, w, 16);
  out[idx] = acc - mx - __logf(s);
}

// ---------------- launcher ----------------

extern "C" void kernel_launch(void* const* d_in, const int* in_sizes, int n_in,
                              void* d_out, int out_size, void* d_ws, size_t ws_size,
                              hipStream_t stream) {
  const float* x      = (const float*)d_in[0];
  const int*   edge   = (const int*)d_in[1];
  const int*   batch  = (const int*)d_in[2];
  const float* W_l1   = (const float*)d_in[3];
  const float* b_l1   = (const float*)d_in[4];
  const float* W_r1   = (const float*)d_in[5];
  const float* b_r1   = (const float*)d_in[6];
  const float* att1   = (const float*)d_in[7];
  const float* bias1  = (const float*)d_in[8];
  const float* W_l2   = (const float*)d_in[9];
  const float* b_l2   = (const float*)d_in[10];
  const float* W_r2   = (const float*)d_in[11];
  const float* b_r2   = (const float*)d_in[12];
  const float* att2   = (const float*)d_in[13];
  const float* bias2  = (const float*)d_in[14];
  const float* W_fc1  = (const float*)d_in[15];
  const float* b_fc1  = (const float*)d_in[16];
  const float* gamma  = (const float*)d_in[17];
  const float* beta   = (const float*)d_in[18];
  const float* W_fc2  = (const float*)d_in[19];
  const float* b_fc2  = (const float*)d_in[20];

  const int* src = edge;
  const int* dst = edge + N_EDGES;

  char* ws = (char*)d_ws;
  size_t off = 0;
  auto alloc = [&](size_t bytes) -> void* {
    off = (off + 255) & ~(size_t)255;
    void* p = ws + off;
    off += bytes;
    return p;
  };
  int* deg      = (int*)alloc((size_t)N_NODES * 4);      // doubles as row_ptr pre-scan
  int* row_ptr  = (int*)alloc((size_t)(N_NODES + 1) * 4);
  int* rank     = (int*)alloc((size_t)N_EDGES * 4);
  int* adj      = (int*)alloc((size_t)N_EDGES * 4);
  int* part     = (int*)alloc((size_t)SCAN_NBLK * 4);
  float* xl     = (float*)alloc((size_t)N_NODES * HID * 4);
  float* xr     = (float*)alloc((size_t)N_NODES * HID * 4);
  float* h      = (float*)alloc((size_t)N_NODES * HID * 4);
  float* gmean  = (float*)alloc((size_t)N_GRAPHS * HID * 4);
  float* y      = (float*)alloc((size_t)N_GRAPHS * HID * 4);
  float* mu     = (float*)alloc(64 * 4);
  float* rstd   = (float*)alloc(64 * 4);

  hipMemsetAsync(deg, 0, (size_t)N_NODES * 4, stream);

  // fused: layer-1 dual GEMM + degree/rank (independent, co-scheduled)
  k_fused_gemm1_degree<<<FUSED_BLOCKS, 256, 0, stream>>>(
      x, W_l1, b_l1, W_r1, b_r1, xl, xr, dst, deg, rank);

  k_scan1<<<SCAN_NBLK, 256, 0, stream>>>(deg, row_ptr, part);
  k_scan2<<<1, 128, 0, stream>>>(part);
  k_scan3<<<(N_NODES + 255) / 256, 256, 0, stream>>>(row_ptr, part);
  k_fill2<<<DEG_BLOCKS, 256, 0, stream>>>(src, dst, rank, row_ptr, adj);

  k_gat<<<(N_NODES + 3) / 4, 256, 0, stream>>>(xl, xr, att1, bias1, row_ptr, adj, h, 1);
  k_dual_gemm<HID><<<(N_NODES + 127) / 128, 256, 0, stream>>>(h, W_l2, b_l2, W_r2, b_r2, xl, xr);
  k_gat<<<(N_NODES + 3) / 4, 256, 0, stream>>>(xl, xr, att2, bias2, row_ptr, adj, h, 0);

  k_pool<<<N_GRAPHS, 256, 0, stream>>>(h, batch, gmean);
  k_head1<<<(N_GRAPHS * 64 + 255) / 256, 256, 0, stream>>>(gmean, W_fc1, b_fc1, y);
  k_bnstats<<<1, 64, 0, stream>>>(y, mu, rstd);
  k_head2<<<(N_GRAPHS * OUT_CH + 255) / 256, 256, 0, stream>>>(y, gamma, beta, mu, rstd,
                                                               W_fc2, b_fc2, (float*)d_out);
}